// Round 14
// baseline (217.385 us; speedup 1.0000x reference)
//
#include <hip/hip_runtime.h>
#include <math.h>

#define NB 8
#define NH 512
#define NW 512
#define ANG512 0.01227184630308513f
#define SPEC_D 16384   // per-depth stride of spec_wr/spec_wi (16*16*8*8)

typedef __attribute__((ext_vector_type(8))) _Float16 f16x8;
typedef __attribute__((ext_vector_type(4))) float    f32x4;

// ---------------------------------------------------------------------------
// k_pre: 512 blocks, 8 rows/block (2 rows per wave).  Row DFT (parity trick)
// + butterfly reduce + per-block kx-rotation partial sum -> P.  (R9-proven.)
// ---------------------------------------------------------------------------
__global__ __launch_bounds__(256) void k_pre(const float* __restrict__ x,
                                             float* __restrict__ P) {
    __shared__ float wred[8][16];
    const int tid = threadIdx.x;
    const int w = tid >> 6, lane = tid & 63;
    const int gid = blockIdx.x;            // 0..511
    const int b = gid >> 6, rg = gid & 63;

    #pragma unroll
    for (int rr = 0; rr < 2; ++rr) {
        const int row = rg * 8 + w + 4 * rr;
        const float* xr = x + ((size_t)(b * NH + row)) * NW;

        float p[16];
        #pragma unroll
        for (int j = 0; j < 16; ++j) p[j] = 0.f;

        #pragma unroll
        for (int j = 0; j < 4; ++j) {
            const int ww = lane + (j << 6);
            const float xa = xr[ww], xb = xr[ww + 256];
            const float a = xa + xb, d = xa - xb;   // tw(w+256)=(-1)^k tw(w)
            float c1, s1;
            __sincosf(ANG512 * (float)ww, &s1, &c1);
            p[0] += a;
            p[1] = fmaf(d, c1, p[1]);
            p[9] = fmaf(-d, s1, p[9]);
            const float c2k = 2.f * c1;
            float ckm = 1.f, skm = 0.f, ck = c1, sk = s1;
            #pragma unroll
            for (int k = 2; k < 8; ++k) {
                const float cn = fmaf(c2k, ck, -ckm);
                const float sn = fmaf(c2k, sk, -skm);
                ckm = ck; skm = sk; ck = cn; sk = sn;
                const float v = (k & 1) ? d : a;
                p[k]     = fmaf(v, ck, p[k]);
                p[8 + k] = fmaf(-v, sk, p[8 + k]);
            }
        }
        #pragma unroll
        for (int m = 1; m < 64; m <<= 1) {
            #pragma unroll
            for (int j = 0; j < 16; ++j) p[j] += __shfl_xor(p[j], m);
        }
        if (lane < 16) wred[w + 4 * rr][lane] = p[lane];
    }
    __syncthreads();

    if (tid < 128) {
        const int kx = tid >> 4, q = tid & 15, qm = q & 7;
        float acc = 0.f;
        #pragma unroll
        for (int r = 0; r < 8; ++r) {
            const int row = rg * 8 + r;
            const int m = (kx * row) & 511;
            float cm, s2;
            __sincosf(ANG512 * (float)m, &s2, &cm);   // e^{-i th m}=(cm,-sm)
            const float rre = wred[r][qm], rim = wred[r][8 + qm];
            acc += (q < 8) ? (rre * cm + rim * s2)
                           : (rim * cm - rre * s2);
        }
        P[((size_t)((b * 64 + rg) * 8 + kx)) * 16 + q] = acc;
    }
}

// ---------------------------------------------------------------------------
// k_modes: 64 blocks, one per (b,kx).  Sum 64 partials -> X2; fc0 fold;
// 3-layer mode recurrence (spec weights straight from global); fold fc1 ->
// AH; kx==0 blocks also write per-batch gv/Kv.  (R9-proven.)
// ---------------------------------------------------------------------------
__global__ __launch_bounds__(256) void k_modes(
        const float* __restrict__ P,
        const float* __restrict__ spec_wr, const float* __restrict__ spec_wi,
        const float* __restrict__ conv_w, const float* __restrict__ conv_b,
        const float* __restrict__ fc0_w, const float* __restrict__ fc0_b,
        const float* __restrict__ fc1_w, const float* __restrict__ fc1_b,
        float* __restrict__ AH, float* __restrict__ gv, float* __restrict__ Kv) {
    __shared__ __align__(16) float sm[2640];
    float* red2  = sm;            // 256
    float* X2    = sm + 256;      // 16
    float* Xr    = sm + 272;      // 128
    float* Xi    = sm + 400;      // 128
    float* Fr    = sm + 528;      // 128
    float* Fi    = sm + 656;      // 128
    float* Ar    = sm + 784;      // 128
    float* Ai    = sm + 912;      // 128
    float* Pm    = sm + 1040;     // 512 [2][256]
    float* fc1_s = sm + 1552;     // 1024
    float* ps    = sm + 2576;     // 64

    const int tid = threadIdx.x;
    const int bid = blockIdx.x;
    const int b = bid >> 3;
    const int kx = bid & 7;

    // ---- Pm[0] = C2*C1, Pm[1] = C2, stage fc1 ----
    {
        const int o = tid >> 4, c = tid & 15;
        float s = 0.f;
        for (int k = 0; k < 16; ++k)
            s += conv_w[512 + o * 16 + k] * conv_w[256 + k * 16 + c];
        Pm[tid] = s;
    }
    Pm[256 + tid] = conv_w[512 + tid];
    #pragma unroll
    for (int k = 0; k < 4; ++k) fc1_s[tid + k * 256] = fc1_w[tid + k * 256];

    // ---- X2 = sum of 64 partials ----
    {
        const int q = tid & 15, c = tid >> 4;
        float acc = 0.f;
        #pragma unroll
        for (int m = 0; m < 4; ++m) {
            const int rg = c + 16 * m;
            acc += P[((size_t)((b * 64 + rg) * 8 + kx)) * 16 + q];
        }
        red2[c * 16 + q] = acc;
    }
    __syncthreads();
    if (tid < 16) {
        float s = 0.f;
        #pragma unroll
        for (int c = 0; c < 16; ++c) s += red2[c * 16 + tid];
        X2[tid] = s;
    }
    __syncthreads();

    // ---- recurrence: thread = (o,ky), tid < 128 ----
    const bool act = (tid < 128);
    const int o = tid >> 3, ky = tid & 7;
    if (act) {
        const float inv = 1.f / (512.f * 512.f);
        float xr0 = fc0_w[o] * X2[ky] * inv;
        float xi0 = fc0_w[o] * X2[8 + ky] * inv;
        if (kx == 0 && ky == 0) xr0 += fc0_b[o];
        Xr[o * 8 + ky] = xr0; Xi[o * 8 + ky] = xi0;
        Ar[o * 8 + ky] = 0.f; Ai[o * 8 + ky] = 0.f;
    }
    __syncthreads();

    for (int dd = 0; dd < 3; ++dd) {
        if (act) {
            float fr = 0.f, fi = 0.f;
            const float* wrp = spec_wr + (size_t)dd * SPEC_D + o * 64 + kx * 8 + ky;
            const float* wip = spec_wi + (size_t)dd * SPEC_D + o * 64 + kx * 8 + ky;
            #pragma unroll
            for (int i = 0; i < 16; ++i) {
                const float wre = wrp[i * 1024];
                const float wim = wip[i * 1024];
                const float xr0 = Xr[i * 8 + ky], xi0 = Xi[i * 8 + ky];
                fr += xr0 * wre - xi0 * wim;
                fi += xr0 * wim + xi0 * wre;
            }
            Fr[o * 8 + ky] = fr; Fi[o * 8 + ky] = fi;
        }
        __syncthreads();
        float xnr = 0.f, xni = 0.f;
        if (act) {
            float ar, ai;
            if (dd == 2) {
                ar = Fr[o * 8 + ky]; ai = Fi[o * 8 + ky];
            } else {
                ar = 0.f; ai = 0.f;
                #pragma unroll
                for (int c = 0; c < 16; ++c) {
                    const float pv = Pm[dd * 256 + o * 16 + c];
                    ar = fmaf(pv, Fr[c * 8 + ky], ar);
                    ai = fmaf(pv, Fi[c * 8 + ky], ai);
                }
            }
            Ar[o * 8 + ky] += ar; Ai[o * 8 + ky] += ai;
            if (dd < 2) {
                const float fr0 = Fr[o * 8 + ky], fi0 = Fi[o * 8 + ky];
                if (ky == 0) {
                    if (kx == 0) { xnr = fr0; xni = 0.f; }
                    else         { xnr = 0.5f * fr0; xni = 0.5f * fi0; }
                } else { xnr = fr0; xni = fi0; }
                #pragma unroll
                for (int c = 0; c < 16; ++c) {
                    const float cc = conv_w[dd * 256 + o * 16 + c];
                    xnr = fmaf(cc, Xr[c * 8 + ky], xnr);
                    xni = fmaf(cc, Xi[c * 8 + ky], xni);
                }
                if (kx == 0 && ky == 0) xnr += conv_b[dd * 16 + o];
            }
        }
        __syncthreads();
        if (act && dd < 2) { Xr[o * 8 + ky] = xnr; Xi[o * 8 + ky] = xni; }
        __syncthreads();
    }

    // ---- fold fc1 -> AH[b,hd,ky,kx] ----
    #pragma unroll
    for (int k2 = 0; k2 < 2; ++k2) {
        const int idx = tid + k2 * 256;      // hd*8 + ky2
        const int hd = idx >> 3, ky2 = idx & 7;
        float ar = 0.f, ai = 0.f;
        #pragma unroll
        for (int c = 0; c < 16; ++c) {
            const float f = fc1_s[c * 64 + hd];
            ar = fmaf(f, Ar[c * 8 + ky2], ar);
            ai = fmaf(f, Ai[c * 8 + ky2], ai);
        }
        const float ck = (ky2 == 0) ? 1.f : 2.f;    // Hermitian doubling
        const size_t off = ((((size_t)(b * 64 + hd)) * 8 + ky2) * 8 + kx) * 2;
        AH[off]     = ck * ar;
        AH[off + 1] = ck * ai;
    }

    // ---- kx==0: per-batch gvec/Kvec copies (weight-only math) ----
    if (kx == 0) {
        if (tid < 16) {
            float su = 0.f, sb = 0.f;
            for (int c = 0; c < 16; ++c) {
                su += conv_w[tid * 16 + c] * fc0_w[c];
                sb += conv_w[tid * 16 + c] * fc0_b[c];
            }
            ps[tid] = su; ps[16 + tid] = sb;
        }
        __syncthreads();
        if (tid < 16) {
            float dv = 0.f, ev = conv_b[32 + tid];
            for (int k = 0; k < 16; ++k) {
                dv += Pm[tid * 16 + k] * ps[k];
                ev += Pm[tid * 16 + k] * (ps[16 + k] + conv_b[k]);
                ev += conv_w[512 + tid * 16 + k] * conv_b[16 + k];
            }
            ps[32 + tid] = dv; ps[48 + tid] = ev;
        }
        __syncthreads();
        if (tid < 64) {
            float g = 0.f, K = fc1_b[tid];
            for (int c = 0; c < 16; ++c) {
                g = fmaf(fc1_w[c * 64 + tid], ps[32 + c], g);
                K = fmaf(fc1_w[c * 64 + tid], ps[48 + c], K);
            }
            gv[b * 64 + tid] = g;
            Kv[b * 64 + tid] = K;
        }
    }
}

// ---------------------------------------------------------------------------
// k_head (MFMA, fp16): 4096 blocks x 256 threads; block = 2 rows x HALF-row
// px range.  R14 change vs R11: occupancy raised via LDS (the R12-measured
// limiter), NOT via VGPR bounds (the R13 mistake).  Ef shrinks to the
// block's 256-px half (8 KB), Apk to 2 rows (8 KB) -> 16 KB total ->
// 8 blocks/CU -> 32 waves/CU.  Grid 4096 = exactly 2 full residency waves.
// Registers: identical dual-tile loop to R11/R12 (measured 52 VGPR);
// __launch_bounds__(256,8) budget 64 > 52, no forced spill.
// Cost: WH build + AH reads duplicated x2 (short phase, +~5MB FETCH).
// Wave w (0..3): row rl=w>>1 of the pair, j-half jh=w&1 for the build;
// main loop: 8 px-tiles (4 dual-tile iters).
// ---------------------------------------------------------------------------
__global__ __launch_bounds__(256, 8) void k_head(
        const float* __restrict__ x, const float* __restrict__ AH,
        const float* __restrict__ gv, const float* __restrict__ Kv,
        const float* __restrict__ fc2_w, const float* __restrict__ fc2_b,
        float* __restrict__ out) {
    __shared__ __align__(16) _Float16 Ef[2][256][8];    // [cos/-sin][px_loc][k] 8KB
    __shared__ __align__(16) _Float16 Apk[2][4][64][8]; // [row][kb][hd][j]     8KB

    const int tid  = threadIdx.x;
    const int lane = tid & 63;
    const int wid  = tid >> 6;           // 0..3
    const int rl   = wid >> 1;           // local row 0..1
    const int jh   = wid & 1;            // build j-half / px-tile half
    const int bid  = blockIdx.x;
    const int b    = bid >> 9;
    const int rem  = bid & 511;
    const int rpp  = rem >> 1;           // row pair 0..255
    const int h    = rem & 1;            // px half of the row
    const int row  = rpp * 2 + rl;

    // ---- E basis build: 256 threads, 1 px each (block's half only) ----
    {
        const int pxg = h * 256 + tid;
        float c1, s1;
        __sincosf(ANG512 * (float)pxg, &s1, &c1);
        float ck = 1.f, sk = 0.f;        // k = 0
        #pragma unroll
        for (int k = 0; k < 8; ++k) {
            Ef[0][tid][k] = (_Float16)ck;     // cos(k th px)
            Ef[1][tid][k] = (_Float16)(-sk);  // -sin(k th px)
            const float cn = ck * c1 - sk * s1;
            const float sn = sk * c1 + ck * s1;
            ck = cn; sk = sn;
        }
    }

    // ---- gh / w2 per-lane preload (hd = t*16 + (lane>>4)*4 + v) ----
    float ghr[16], w2r[16];
    {
        const int lg = lane >> 4;
        #pragma unroll
        for (int t = 0; t < 4; ++t)
            #pragma unroll
            for (int v = 0; v < 4; ++v) {
                const int hd = t * 16 + lg * 4 + v;
                ghr[t * 4 + v] = gv[b * 64 + hd];
                w2r[t * 4 + v] = fc2_w[hd];
            }
    }

    // ---- WH build (fp32) -> fp16 hi/lo into Apk[rl]; wave does its j-half --
    {
        float c1, s1;
        __sincosf(ANG512 * (float)row, &s1, &c1);
        float ctr[8], str[8];
        ctr[0] = 1.f; str[0] = 0.f; ctr[1] = c1; str[1] = s1;
        const float c2k = 2.f * c1;
        #pragma unroll
        for (int k = 2; k < 8; ++k) {
            ctr[k] = fmaf(c2k, ctr[k - 1], -ctr[k - 2]);
            str[k] = fmaf(c2k, str[k - 1], -str[k - 2]);
        }
        #pragma unroll
        for (int j = 0; j < 4; ++j) {
            const int idx = lane + (jh * 4 + j) * 64;   // hd*8 + ky
            const int hd = idx >> 3, ky = idx & 7;
            const float4* ap = (const float4*)(AH + ((size_t)(b * 64 + hd) * 8 + ky) * 16);
            const float4 a0 = ap[0], a1 = ap[1], a2 = ap[2], a3 = ap[3];
            float wr = a0.x, wi = a0.y;      // kx=0
            wr = fmaf(a0.z, ctr[1], wr); wr = fmaf(-a0.w, str[1], wr);
            wi = fmaf(a0.z, str[1], wi); wi = fmaf(a0.w, ctr[1], wi);
            wr = fmaf(a1.x, ctr[2], wr); wr = fmaf(-a1.y, str[2], wr);
            wi = fmaf(a1.x, str[2], wi); wi = fmaf(a1.y, ctr[2], wi);
            wr = fmaf(a1.z, ctr[3], wr); wr = fmaf(-a1.w, str[3], wr);
            wi = fmaf(a1.z, str[3], wi); wi = fmaf(a1.w, ctr[3], wi);
            wr = fmaf(a2.x, ctr[4], wr); wr = fmaf(-a2.y, str[4], wr);
            wi = fmaf(a2.x, str[4], wi); wi = fmaf(a2.y, ctr[4], wi);
            wr = fmaf(a2.z, ctr[5], wr); wr = fmaf(-a2.w, str[5], wr);
            wi = fmaf(a2.z, str[5], wi); wi = fmaf(a2.w, ctr[5], wi);
            wr = fmaf(a3.x, ctr[6], wr); wr = fmaf(-a3.y, str[6], wr);
            wi = fmaf(a3.x, str[6], wi); wi = fmaf(a3.y, ctr[6], wi);
            wr = fmaf(a3.z, ctr[7], wr); wr = fmaf(-a3.w, str[7], wr);
            wi = fmaf(a3.w, ctr[7], wi); wi = fmaf(a3.z, str[7], wi);
            if (ky == 0) wr += Kv[b * 64 + hd];
            const _Float16 hr  = (_Float16)wr;
            const _Float16 hi_ = (_Float16)wi;
            Apk[rl][0][hd][ky] = hr;                          // WHr hi (K 0..7)
            Apk[rl][1][hd][ky] = hi_;                         // WHi hi (K 8..15)
            Apk[rl][2][hd][ky] = (_Float16)(wr - (float)hr);  // WHr lo (K 16..23)
            Apk[rl][3][hd][ky] = (_Float16)(wi - (float)hi_); // WHi lo (K 24..31)
        }
    }
    __syncthreads();

    // ---- A fragments (resident in VGPRs) ----
    f16x8 a1[4];
    {
        const int kb = lane >> 4, m = lane & 15;
        #pragma unroll
        for (int t = 0; t < 4; ++t)
            a1[t] = *(const f16x8*)&Apk[rl][kb][t * 16 + m][0];
    }

    // ---- dual-tile MFMA + epilogue: 4 iters x 2 px-tiles (wave's 8 tiles) --
    const int eb = (lane >> 4) & 1, n = lane & 15;
    const float fc2b = fc2_b[0];
    const float* xrow = x + ((size_t)(b * NH + row)) * NW;
    float* orow = out + ((size_t)(b * NH + row)) * NW;
    const int tb = jh * 8;               // local tile base (block-local Ef)
    const int gb = h * 16 + tb;          // global tile base

    f16x8 bn0 = *(const f16x8*)&Ef[eb][tb * 16 + n][0];
    f16x8 bn1 = *(const f16x8*)&Ef[eb][(tb + 1) * 16 + n][0];
    float xn0 = xrow[gb * 16 + n];
    float xn1 = xrow[(gb + 1) * 16 + n];

    #pragma unroll
    for (int it = 0; it < 4; ++it) {
        const f16x8 b0 = bn0, b1 = bn1;
        const float x0 = xn0, x1 = xn1;
        if (it < 3) {                        // prefetch iter+1 (both tiles)
            const int tl = tb + 2 * (it + 1);
            const int gl = gb + 2 * (it + 1);
            bn0 = *(const f16x8*)&Ef[eb][tl * 16 + n][0];
            bn1 = *(const f16x8*)&Ef[eb][(tl + 1) * 16 + n][0];
            xn0 = xrow[gl * 16 + n];
            xn1 = xrow[(gl + 1) * 16 + n];
        }
        f32x4 c0[4], c1[4];
        #pragma unroll
        for (int t = 0; t < 4; ++t) {
            c0[t] = (f32x4){0.f, 0.f, 0.f, 0.f};
            c1[t] = (f32x4){0.f, 0.f, 0.f, 0.f};
            c0[t] = __builtin_amdgcn_mfma_f32_16x16x32_f16(a1[t], b0, c0[t], 0, 0, 0);
            c1[t] = __builtin_amdgcn_mfma_f32_16x16x32_f16(a1[t], b1, c1[t], 0, 0, 0);
        }
        float p0[4] = {0.f, 0.f, 0.f, 0.f};
        float p1[4] = {0.f, 0.f, 0.f, 0.f};
        #pragma unroll
        for (int t = 0; t < 4; ++t)
            #pragma unroll
            for (int v = 0; v < 4; ++v) {
                float s0 = fmaf(ghr[t * 4 + v], x0, c0[t][v]);
                float s1 = fmaf(ghr[t * 4 + v], x1, c1[t][v]);
                s0 = fmaxf(s0, 0.f);
                s1 = fmaxf(s1, 0.f);
                p0[v] = fmaf(s0, w2r[t * 4 + v], p0[v]);
                p1[v] = fmaf(s1, w2r[t * 4 + v], p1[v]);
            }
        float v0 = (p0[0] + p0[1]) + (p0[2] + p0[3]);
        float v1 = (p1[0] + p1[1]) + (p1[2] + p1[3]);
        v0 += __shfl_xor(v0, 16);
        v1 += __shfl_xor(v1, 16);
        v0 += __shfl_xor(v0, 32);
        v1 += __shfl_xor(v1, 32);
        if (lane < 16) {
            const int g0 = gb + 2 * it;
            orow[g0 * 16 + lane]        = v0 + fc2b;
            orow[(g0 + 1) * 16 + lane]  = v1 + fc2b;
        }
    }
}

// ---------------------------------------------------------------------------
extern "C" void kernel_launch(void* const* d_in, const int* in_sizes, int n_in,
                              void* d_out, int out_size, void* d_ws, size_t ws_size,
                              hipStream_t stream) {
    const float* x       = (const float*)d_in[0];
    const float* fc0_w   = (const float*)d_in[1];
    const float* fc0_b   = (const float*)d_in[2];
    const float* spec_wr = (const float*)d_in[3];
    const float* spec_wi = (const float*)d_in[4];
    const float* conv_w  = (const float*)d_in[5];
    const float* conv_b  = (const float*)d_in[6];
    const float* fc1_w   = (const float*)d_in[7];
    const float* fc1_b   = (const float*)d_in[8];
    const float* fc2_w   = (const float*)d_in[9];
    const float* fc2_b   = (const float*)d_in[10];
    float* outp = (float*)d_out;

    char* ws = (char*)d_ws;
    float* P  = (float*)ws;                       // 8*64*8*16 floats = 256 KB
    float* AH = (float*)(ws + 262144);            // 8*64*64*2 floats = 256 KB
    float* gv = (float*)(ws + 524288);            // 8*64 floats = 2 KB
    float* Kv = (float*)(ws + 526336);            // 8*64 floats = 2 KB

    k_pre<<<512, 256, 0, stream>>>(x, P);
    k_modes<<<64, 256, 0, stream>>>(P, spec_wr, spec_wi, conv_w, conv_b,
                                    fc0_w, fc0_b, fc1_w, fc1_b, AH, gv, Kv);
    k_head<<<4096, 256, 0, stream>>>(x, AH, gv, Kv, fc2_w, fc2_b, outp);
}

// Round 15
// 158.308 us; speedup vs baseline: 1.3732x; 1.3732x over previous
//
#include <hip/hip_runtime.h>
#include <math.h>

#define NB 8
#define NH 512
#define NW 512
#define ANG512 0.01227184630308513f
#define SPEC_D 16384   // per-depth stride of spec_wr/spec_wi (16*16*8*8)

typedef __attribute__((ext_vector_type(8))) _Float16 f16x8;
typedef __attribute__((ext_vector_type(4))) float    f32x4;

// ---------------------------------------------------------------------------
// k_pre: 512 blocks, 8 rows/block (2 rows per wave).  Row DFT (parity trick)
// + butterfly reduce + per-block kx-rotation partial sum -> P.  (R9-proven.)
// ---------------------------------------------------------------------------
__global__ __launch_bounds__(256) void k_pre(const float* __restrict__ x,
                                             float* __restrict__ P) {
    __shared__ float wred[8][16];
    const int tid = threadIdx.x;
    const int w = tid >> 6, lane = tid & 63;
    const int gid = blockIdx.x;            // 0..511
    const int b = gid >> 6, rg = gid & 63;

    #pragma unroll
    for (int rr = 0; rr < 2; ++rr) {
        const int row = rg * 8 + w + 4 * rr;
        const float* xr = x + ((size_t)(b * NH + row)) * NW;

        float p[16];
        #pragma unroll
        for (int j = 0; j < 16; ++j) p[j] = 0.f;

        #pragma unroll
        for (int j = 0; j < 4; ++j) {
            const int ww = lane + (j << 6);
            const float xa = xr[ww], xb = xr[ww + 256];
            const float a = xa + xb, d = xa - xb;   // tw(w+256)=(-1)^k tw(w)
            float c1, s1;
            __sincosf(ANG512 * (float)ww, &s1, &c1);
            p[0] += a;
            p[1] = fmaf(d, c1, p[1]);
            p[9] = fmaf(-d, s1, p[9]);
            const float c2k = 2.f * c1;
            float ckm = 1.f, skm = 0.f, ck = c1, sk = s1;
            #pragma unroll
            for (int k = 2; k < 8; ++k) {
                const float cn = fmaf(c2k, ck, -ckm);
                const float sn = fmaf(c2k, sk, -skm);
                ckm = ck; skm = sk; ck = cn; sk = sn;
                const float v = (k & 1) ? d : a;
                p[k]     = fmaf(v, ck, p[k]);
                p[8 + k] = fmaf(-v, sk, p[8 + k]);
            }
        }
        #pragma unroll
        for (int m = 1; m < 64; m <<= 1) {
            #pragma unroll
            for (int j = 0; j < 16; ++j) p[j] += __shfl_xor(p[j], m);
        }
        if (lane < 16) wred[w + 4 * rr][lane] = p[lane];
    }
    __syncthreads();

    if (tid < 128) {
        const int kx = tid >> 4, q = tid & 15, qm = q & 7;
        float acc = 0.f;
        #pragma unroll
        for (int r = 0; r < 8; ++r) {
            const int row = rg * 8 + r;
            const int m = (kx * row) & 511;
            float cm, s2;
            __sincosf(ANG512 * (float)m, &s2, &cm);   // e^{-i th m}=(cm,-sm)
            const float rre = wred[r][qm], rim = wred[r][8 + qm];
            acc += (q < 8) ? (rre * cm + rim * s2)
                           : (rim * cm - rre * s2);
        }
        P[((size_t)((b * 64 + rg) * 8 + kx)) * 16 + q] = acc;
    }
}

// ---------------------------------------------------------------------------
// k_modes: 64 blocks, one per (b,kx).  Sum 64 partials -> X2; fc0 fold;
// 3-layer mode recurrence (spec weights straight from global); fold fc1 ->
// AH; kx==0 blocks also write per-batch gv/Kv.  (R9-proven.)
// ---------------------------------------------------------------------------
__global__ __launch_bounds__(256) void k_modes(
        const float* __restrict__ P,
        const float* __restrict__ spec_wr, const float* __restrict__ spec_wi,
        const float* __restrict__ conv_w, const float* __restrict__ conv_b,
        const float* __restrict__ fc0_w, const float* __restrict__ fc0_b,
        const float* __restrict__ fc1_w, const float* __restrict__ fc1_b,
        float* __restrict__ AH, float* __restrict__ gv, float* __restrict__ Kv) {
    __shared__ __align__(16) float sm[2640];
    float* red2  = sm;            // 256
    float* X2    = sm + 256;      // 16
    float* Xr    = sm + 272;      // 128
    float* Xi    = sm + 400;      // 128
    float* Fr    = sm + 528;      // 128
    float* Fi    = sm + 656;      // 128
    float* Ar    = sm + 784;      // 128
    float* Ai    = sm + 912;      // 128
    float* Pm    = sm + 1040;     // 512 [2][256]
    float* fc1_s = sm + 1552;     // 1024
    float* ps    = sm + 2576;     // 64

    const int tid = threadIdx.x;
    const int bid = blockIdx.x;
    const int b = bid >> 3;
    const int kx = bid & 7;

    // ---- Pm[0] = C2*C1, Pm[1] = C2, stage fc1 ----
    {
        const int o = tid >> 4, c = tid & 15;
        float s = 0.f;
        for (int k = 0; k < 16; ++k)
            s += conv_w[512 + o * 16 + k] * conv_w[256 + k * 16 + c];
        Pm[tid] = s;
    }
    Pm[256 + tid] = conv_w[512 + tid];
    #pragma unroll
    for (int k = 0; k < 4; ++k) fc1_s[tid + k * 256] = fc1_w[tid + k * 256];

    // ---- X2 = sum of 64 partials ----
    {
        const int q = tid & 15, c = tid >> 4;
        float acc = 0.f;
        #pragma unroll
        for (int m = 0; m < 4; ++m) {
            const int rg = c + 16 * m;
            acc += P[((size_t)((b * 64 + rg) * 8 + kx)) * 16 + q];
        }
        red2[c * 16 + q] = acc;
    }
    __syncthreads();
    if (tid < 16) {
        float s = 0.f;
        #pragma unroll
        for (int c = 0; c < 16; ++c) s += red2[c * 16 + tid];
        X2[tid] = s;
    }
    __syncthreads();

    // ---- recurrence: thread = (o,ky), tid < 128 ----
    const bool act = (tid < 128);
    const int o = tid >> 3, ky = tid & 7;
    if (act) {
        const float inv = 1.f / (512.f * 512.f);
        float xr0 = fc0_w[o] * X2[ky] * inv;
        float xi0 = fc0_w[o] * X2[8 + ky] * inv;
        if (kx == 0 && ky == 0) xr0 += fc0_b[o];
        Xr[o * 8 + ky] = xr0; Xi[o * 8 + ky] = xi0;
        Ar[o * 8 + ky] = 0.f; Ai[o * 8 + ky] = 0.f;
    }
    __syncthreads();

    for (int dd = 0; dd < 3; ++dd) {
        if (act) {
            float fr = 0.f, fi = 0.f;
            const float* wrp = spec_wr + (size_t)dd * SPEC_D + o * 64 + kx * 8 + ky;
            const float* wip = spec_wi + (size_t)dd * SPEC_D + o * 64 + kx * 8 + ky;
            #pragma unroll
            for (int i = 0; i < 16; ++i) {
                const float wre = wrp[i * 1024];
                const float wim = wip[i * 1024];
                const float xr0 = Xr[i * 8 + ky], xi0 = Xi[i * 8 + ky];
                fr += xr0 * wre - xi0 * wim;
                fi += xr0 * wim + xi0 * wre;
            }
            Fr[o * 8 + ky] = fr; Fi[o * 8 + ky] = fi;
        }
        __syncthreads();
        float xnr = 0.f, xni = 0.f;
        if (act) {
            float ar, ai;
            if (dd == 2) {
                ar = Fr[o * 8 + ky]; ai = Fi[o * 8 + ky];
            } else {
                ar = 0.f; ai = 0.f;
                #pragma unroll
                for (int c = 0; c < 16; ++c) {
                    const float pv = Pm[dd * 256 + o * 16 + c];
                    ar = fmaf(pv, Fr[c * 8 + ky], ar);
                    ai = fmaf(pv, Fi[c * 8 + ky], ai);
                }
            }
            Ar[o * 8 + ky] += ar; Ai[o * 8 + ky] += ai;
            if (dd < 2) {
                const float fr0 = Fr[o * 8 + ky], fi0 = Fi[o * 8 + ky];
                if (ky == 0) {
                    if (kx == 0) { xnr = fr0; xni = 0.f; }
                    else         { xnr = 0.5f * fr0; xni = 0.5f * fi0; }
                } else { xnr = fr0; xni = fi0; }
                #pragma unroll
                for (int c = 0; c < 16; ++c) {
                    const float cc = conv_w[dd * 256 + o * 16 + c];
                    xnr = fmaf(cc, Xr[c * 8 + ky], xnr);
                    xni = fmaf(cc, Xi[c * 8 + ky], xni);
                }
                if (kx == 0 && ky == 0) xnr += conv_b[dd * 16 + o];
            }
        }
        __syncthreads();
        if (act && dd < 2) { Xr[o * 8 + ky] = xnr; Xi[o * 8 + ky] = xni; }
        __syncthreads();
    }

    // ---- fold fc1 -> AH[b,hd,ky,kx] ----
    #pragma unroll
    for (int k2 = 0; k2 < 2; ++k2) {
        const int idx = tid + k2 * 256;      // hd*8 + ky2
        const int hd = idx >> 3, ky2 = idx & 7;
        float ar = 0.f, ai = 0.f;
        #pragma unroll
        for (int c = 0; c < 16; ++c) {
            const float f = fc1_s[c * 64 + hd];
            ar = fmaf(f, Ar[c * 8 + ky2], ar);
            ai = fmaf(f, Ai[c * 8 + ky2], ai);
        }
        const float ck = (ky2 == 0) ? 1.f : 2.f;    // Hermitian doubling
        const size_t off = ((((size_t)(b * 64 + hd)) * 8 + ky2) * 8 + kx) * 2;
        AH[off]     = ck * ar;
        AH[off + 1] = ck * ai;
    }

    // ---- kx==0: per-batch gvec/Kvec copies (weight-only math) ----
    if (kx == 0) {
        if (tid < 16) {
            float su = 0.f, sb = 0.f;
            for (int c = 0; c < 16; ++c) {
                su += conv_w[tid * 16 + c] * fc0_w[c];
                sb += conv_w[tid * 16 + c] * fc0_b[c];
            }
            ps[tid] = su; ps[16 + tid] = sb;
        }
        __syncthreads();
        if (tid < 16) {
            float dv = 0.f, ev = conv_b[32 + tid];
            for (int k = 0; k < 16; ++k) {
                dv += Pm[tid * 16 + k] * ps[k];
                ev += Pm[tid * 16 + k] * (ps[16 + k] + conv_b[k]);
                ev += conv_w[512 + tid * 16 + k] * conv_b[16 + k];
            }
            ps[32 + tid] = dv; ps[48 + tid] = ev;
        }
        __syncthreads();
        if (tid < 64) {
            float g = 0.f, K = fc1_b[tid];
            for (int c = 0; c < 16; ++c) {
                g = fmaf(fc1_w[c * 64 + tid], ps[32 + c], g);
                K = fmaf(fc1_w[c * 64 + tid], ps[48 + c], K);
            }
            gv[b * 64 + tid] = g;
            Kv[b * 64 + tid] = K;
        }
    }
}

// ---------------------------------------------------------------------------
// k_head (MFMA, fp16): 4096 blocks x 256 threads; block = 2 rows x HALF-row
// px range (R14 16KB-LDS structure).  R15 fix vs R13/R14: the occupancy ask
// matches the UNIFIED register file (gfx950: VGPR+AGPR share one budget).
// Working set = ~52 arch VGPR + 32 MFMA accumulators = ~84 unified ->
// max 6 waves/SIMD (512/6 = 85).  __launch_bounds__(256, 6) budgets 85:
// no spill (R13/R14 forced 64 and spilled to scratch at 300MB FETCH).
// LDS 16 KB -> LDS permits 8 blocks/CU; VGPR limits to 6 -> 24 waves/CU,
// 1.5x R11/R12's 16.
// ---------------------------------------------------------------------------
__global__ __launch_bounds__(256, 6) void k_head(
        const float* __restrict__ x, const float* __restrict__ AH,
        const float* __restrict__ gv, const float* __restrict__ Kv,
        const float* __restrict__ fc2_w, const float* __restrict__ fc2_b,
        float* __restrict__ out) {
    __shared__ __align__(16) _Float16 Ef[2][256][8];    // [cos/-sin][px_loc][k] 8KB
    __shared__ __align__(16) _Float16 Apk[2][4][64][8]; // [row][kb][hd][j]     8KB

    const int tid  = threadIdx.x;
    const int lane = tid & 63;
    const int wid  = tid >> 6;           // 0..3
    const int rl   = wid >> 1;           // local row 0..1
    const int jh   = wid & 1;            // build j-half / px-tile half
    const int bid  = blockIdx.x;
    const int b    = bid >> 9;
    const int rem  = bid & 511;
    const int rpp  = rem >> 1;           // row pair 0..255
    const int h    = rem & 1;            // px half of the row
    const int row  = rpp * 2 + rl;

    // ---- E basis build: 256 threads, 1 px each (block's half only) ----
    {
        const int pxg = h * 256 + tid;
        float c1, s1;
        __sincosf(ANG512 * (float)pxg, &s1, &c1);
        float ck = 1.f, sk = 0.f;        // k = 0
        #pragma unroll
        for (int k = 0; k < 8; ++k) {
            Ef[0][tid][k] = (_Float16)ck;     // cos(k th px)
            Ef[1][tid][k] = (_Float16)(-sk);  // -sin(k th px)
            const float cn = ck * c1 - sk * s1;
            const float sn = sk * c1 + ck * s1;
            ck = cn; sk = sn;
        }
    }

    // ---- gh / w2 per-lane preload (hd = t*16 + (lane>>4)*4 + v) ----
    float ghr[16], w2r[16];
    {
        const int lg = lane >> 4;
        #pragma unroll
        for (int t = 0; t < 4; ++t)
            #pragma unroll
            for (int v = 0; v < 4; ++v) {
                const int hd = t * 16 + lg * 4 + v;
                ghr[t * 4 + v] = gv[b * 64 + hd];
                w2r[t * 4 + v] = fc2_w[hd];
            }
    }

    // ---- WH build (fp32) -> fp16 hi/lo into Apk[rl]; wave does its j-half --
    {
        float c1, s1;
        __sincosf(ANG512 * (float)row, &s1, &c1);
        float ctr[8], str[8];
        ctr[0] = 1.f; str[0] = 0.f; ctr[1] = c1; str[1] = s1;
        const float c2k = 2.f * c1;
        #pragma unroll
        for (int k = 2; k < 8; ++k) {
            ctr[k] = fmaf(c2k, ctr[k - 1], -ctr[k - 2]);
            str[k] = fmaf(c2k, str[k - 1], -str[k - 2]);
        }
        #pragma unroll
        for (int j = 0; j < 4; ++j) {
            const int idx = lane + (jh * 4 + j) * 64;   // hd*8 + ky
            const int hd = idx >> 3, ky = idx & 7;
            const float4* ap = (const float4*)(AH + ((size_t)(b * 64 + hd) * 8 + ky) * 16);
            const float4 a0 = ap[0], a1 = ap[1], a2 = ap[2], a3 = ap[3];
            float wr = a0.x, wi = a0.y;      // kx=0
            wr = fmaf(a0.z, ctr[1], wr); wr = fmaf(-a0.w, str[1], wr);
            wi = fmaf(a0.z, str[1], wi); wi = fmaf(a0.w, ctr[1], wi);
            wr = fmaf(a1.x, ctr[2], wr); wr = fmaf(-a1.y, str[2], wr);
            wi = fmaf(a1.x, str[2], wi); wi = fmaf(a1.y, ctr[2], wi);
            wr = fmaf(a1.z, ctr[3], wr); wr = fmaf(-a1.w, str[3], wr);
            wi = fmaf(a1.z, str[3], wi); wi = fmaf(a1.w, ctr[3], wi);
            wr = fmaf(a2.x, ctr[4], wr); wr = fmaf(-a2.y, str[4], wr);
            wi = fmaf(a2.x, str[4], wi); wi = fmaf(a2.y, ctr[4], wi);
            wr = fmaf(a2.z, ctr[5], wr); wr = fmaf(-a2.w, str[5], wr);
            wi = fmaf(a2.z, str[5], wi); wi = fmaf(a2.w, ctr[5], wi);
            wr = fmaf(a3.x, ctr[6], wr); wr = fmaf(-a3.y, str[6], wr);
            wi = fmaf(a3.x, str[6], wi); wi = fmaf(a3.y, ctr[6], wi);
            wr = fmaf(a3.z, ctr[7], wr); wr = fmaf(-a3.w, str[7], wr);
            wi = fmaf(a3.w, ctr[7], wi); wi = fmaf(a3.z, str[7], wi);
            if (ky == 0) wr += Kv[b * 64 + hd];
            const _Float16 hr  = (_Float16)wr;
            const _Float16 hi_ = (_Float16)wi;
            Apk[rl][0][hd][ky] = hr;                          // WHr hi (K 0..7)
            Apk[rl][1][hd][ky] = hi_;                         // WHi hi (K 8..15)
            Apk[rl][2][hd][ky] = (_Float16)(wr - (float)hr);  // WHr lo (K 16..23)
            Apk[rl][3][hd][ky] = (_Float16)(wi - (float)hi_); // WHi lo (K 24..31)
        }
    }
    __syncthreads();

    // ---- A fragments (resident in VGPRs) ----
    f16x8 a1[4];
    {
        const int kb = lane >> 4, m = lane & 15;
        #pragma unroll
        for (int t = 0; t < 4; ++t)
            a1[t] = *(const f16x8*)&Apk[rl][kb][t * 16 + m][0];
    }

    // ---- dual-tile MFMA + epilogue: 4 iters x 2 px-tiles (wave's 8 tiles) --
    const int eb = (lane >> 4) & 1, n = lane & 15;
    const float fc2b = fc2_b[0];
    const float* xrow = x + ((size_t)(b * NH + row)) * NW;
    float* orow = out + ((size_t)(b * NH + row)) * NW;
    const int tb = jh * 8;               // local tile base (block-local Ef)
    const int gb = h * 16 + tb;          // global tile base

    f16x8 bn0 = *(const f16x8*)&Ef[eb][tb * 16 + n][0];
    f16x8 bn1 = *(const f16x8*)&Ef[eb][(tb + 1) * 16 + n][0];
    float xn0 = xrow[gb * 16 + n];
    float xn1 = xrow[(gb + 1) * 16 + n];

    #pragma unroll
    for (int it = 0; it < 4; ++it) {
        const f16x8 b0 = bn0, b1 = bn1;
        const float x0 = xn0, x1 = xn1;
        if (it < 3) {                        // prefetch iter+1 (both tiles)
            const int tl = tb + 2 * (it + 1);
            const int gl = gb + 2 * (it + 1);
            bn0 = *(const f16x8*)&Ef[eb][tl * 16 + n][0];
            bn1 = *(const f16x8*)&Ef[eb][(tl + 1) * 16 + n][0];
            xn0 = xrow[gl * 16 + n];
            xn1 = xrow[(gl + 1) * 16 + n];
        }
        f32x4 c0[4], c1[4];
        #pragma unroll
        for (int t = 0; t < 4; ++t) {
            c0[t] = (f32x4){0.f, 0.f, 0.f, 0.f};
            c1[t] = (f32x4){0.f, 0.f, 0.f, 0.f};
            c0[t] = __builtin_amdgcn_mfma_f32_16x16x32_f16(a1[t], b0, c0[t], 0, 0, 0);
            c1[t] = __builtin_amdgcn_mfma_f32_16x16x32_f16(a1[t], b1, c1[t], 0, 0, 0);
        }
        float p0[4] = {0.f, 0.f, 0.f, 0.f};
        float p1[4] = {0.f, 0.f, 0.f, 0.f};
        #pragma unroll
        for (int t = 0; t < 4; ++t)
            #pragma unroll
            for (int v = 0; v < 4; ++v) {
                float s0 = fmaf(ghr[t * 4 + v], x0, c0[t][v]);
                float s1 = fmaf(ghr[t * 4 + v], x1, c1[t][v]);
                s0 = fmaxf(s0, 0.f);
                s1 = fmaxf(s1, 0.f);
                p0[v] = fmaf(s0, w2r[t * 4 + v], p0[v]);
                p1[v] = fmaf(s1, w2r[t * 4 + v], p1[v]);
            }
        float v0 = (p0[0] + p0[1]) + (p0[2] + p0[3]);
        float v1 = (p1[0] + p1[1]) + (p1[2] + p1[3]);
        v0 += __shfl_xor(v0, 16);
        v1 += __shfl_xor(v1, 16);
        v0 += __shfl_xor(v0, 32);
        v1 += __shfl_xor(v1, 32);
        if (lane < 16) {
            const int g0 = gb + 2 * it;
            orow[g0 * 16 + lane]        = v0 + fc2b;
            orow[(g0 + 1) * 16 + lane]  = v1 + fc2b;
        }
    }
}

// ---------------------------------------------------------------------------
extern "C" void kernel_launch(void* const* d_in, const int* in_sizes, int n_in,
                              void* d_out, int out_size, void* d_ws, size_t ws_size,
                              hipStream_t stream) {
    const float* x       = (const float*)d_in[0];
    const float* fc0_w   = (const float*)d_in[1];
    const float* fc0_b   = (const float*)d_in[2];
    const float* spec_wr = (const float*)d_in[3];
    const float* spec_wi = (const float*)d_in[4];
    const float* conv_w  = (const float*)d_in[5];
    const float* conv_b  = (const float*)d_in[6];
    const float* fc1_w   = (const float*)d_in[7];
    const float* fc1_b   = (const float*)d_in[8];
    const float* fc2_w   = (const float*)d_in[9];
    const float* fc2_b   = (const float*)d_in[10];
    float* outp = (float*)d_out;

    char* ws = (char*)d_ws;
    float* P  = (float*)ws;                       // 8*64*8*16 floats = 256 KB
    float* AH = (float*)(ws + 262144);            // 8*64*64*2 floats = 256 KB
    float* gv = (float*)(ws + 524288);            // 8*64 floats = 2 KB
    float* Kv = (float*)(ws + 526336);            // 8*64 floats = 2 KB

    k_pre<<<512, 256, 0, stream>>>(x, P);
    k_modes<<<64, 256, 0, stream>>>(P, spec_wr, spec_wi, conv_w, conv_b,
                                    fc0_w, fc0_b, fc1_w, fc1_b, AH, gv, Kv);
    k_head<<<4096, 256, 0, stream>>>(x, AH, gv, Kv, fc2_w, fc2_b, outp);
}

// Round 16
// 116.080 us; speedup vs baseline: 1.8727x; 1.3638x over previous
//
#include <hip/hip_runtime.h>
#include <math.h>

#define NB 8
#define NH 512
#define NW 512
#define ANG512 0.01227184630308513f
#define SPEC_D 16384   // per-depth stride of spec_wr/spec_wi (16*16*8*8)

typedef __attribute__((ext_vector_type(8))) _Float16 f16x8;
typedef __attribute__((ext_vector_type(4))) float    f32x4;

// ---------------------------------------------------------------------------
// k_pre: 512 blocks, 8 rows/block (2 rows per wave).  Row DFT (parity trick)
// + butterfly reduce + per-block kx-rotation partial sum -> P.  (R9-proven.)
// ---------------------------------------------------------------------------
__global__ __launch_bounds__(256) void k_pre(const float* __restrict__ x,
                                             float* __restrict__ P) {
    __shared__ float wred[8][16];
    const int tid = threadIdx.x;
    const int w = tid >> 6, lane = tid & 63;
    const int gid = blockIdx.x;            // 0..511
    const int b = gid >> 6, rg = gid & 63;

    #pragma unroll
    for (int rr = 0; rr < 2; ++rr) {
        const int row = rg * 8 + w + 4 * rr;
        const float* xr = x + ((size_t)(b * NH + row)) * NW;

        float p[16];
        #pragma unroll
        for (int j = 0; j < 16; ++j) p[j] = 0.f;

        #pragma unroll
        for (int j = 0; j < 4; ++j) {
            const int ww = lane + (j << 6);
            const float xa = xr[ww], xb = xr[ww + 256];
            const float a = xa + xb, d = xa - xb;   // tw(w+256)=(-1)^k tw(w)
            float c1, s1;
            __sincosf(ANG512 * (float)ww, &s1, &c1);
            p[0] += a;
            p[1] = fmaf(d, c1, p[1]);
            p[9] = fmaf(-d, s1, p[9]);
            const float c2k = 2.f * c1;
            float ckm = 1.f, skm = 0.f, ck = c1, sk = s1;
            #pragma unroll
            for (int k = 2; k < 8; ++k) {
                const float cn = fmaf(c2k, ck, -ckm);
                const float sn = fmaf(c2k, sk, -skm);
                ckm = ck; skm = sk; ck = cn; sk = sn;
                const float v = (k & 1) ? d : a;
                p[k]     = fmaf(v, ck, p[k]);
                p[8 + k] = fmaf(-v, sk, p[8 + k]);
            }
        }
        #pragma unroll
        for (int m = 1; m < 64; m <<= 1) {
            #pragma unroll
            for (int j = 0; j < 16; ++j) p[j] += __shfl_xor(p[j], m);
        }
        if (lane < 16) wred[w + 4 * rr][lane] = p[lane];
    }
    __syncthreads();

    if (tid < 128) {
        const int kx = tid >> 4, q = tid & 15, qm = q & 7;
        float acc = 0.f;
        #pragma unroll
        for (int r = 0; r < 8; ++r) {
            const int row = rg * 8 + r;
            const int m = (kx * row) & 511;
            float cm, s2;
            __sincosf(ANG512 * (float)m, &s2, &cm);   // e^{-i th m}=(cm,-sm)
            const float rre = wred[r][qm], rim = wred[r][8 + qm];
            acc += (q < 8) ? (rre * cm + rim * s2)
                           : (rim * cm - rre * s2);
        }
        P[((size_t)((b * 64 + rg) * 8 + kx)) * 16 + q] = acc;
    }
}

// ---------------------------------------------------------------------------
// k_modes: 64 blocks, one per (b,kx).  Sum 64 partials -> X2; fc0 fold;
// 3-layer mode recurrence (spec weights straight from global); fold fc1 ->
// AH; kx==0 blocks also write per-batch gv/Kv.  (R9-proven.)
// ---------------------------------------------------------------------------
__global__ __launch_bounds__(256) void k_modes(
        const float* __restrict__ P,
        const float* __restrict__ spec_wr, const float* __restrict__ spec_wi,
        const float* __restrict__ conv_w, const float* __restrict__ conv_b,
        const float* __restrict__ fc0_w, const float* __restrict__ fc0_b,
        const float* __restrict__ fc1_w, const float* __restrict__ fc1_b,
        float* __restrict__ AH, float* __restrict__ gv, float* __restrict__ Kv) {
    __shared__ __align__(16) float sm[2640];
    float* red2  = sm;            // 256
    float* X2    = sm + 256;      // 16
    float* Xr    = sm + 272;      // 128
    float* Xi    = sm + 400;      // 128
    float* Fr    = sm + 528;      // 128
    float* Fi    = sm + 656;      // 128
    float* Ar    = sm + 784;      // 128
    float* Ai    = sm + 912;      // 128
    float* Pm    = sm + 1040;     // 512 [2][256]
    float* fc1_s = sm + 1552;     // 1024
    float* ps    = sm + 2576;     // 64

    const int tid = threadIdx.x;
    const int bid = blockIdx.x;
    const int b = bid >> 3;
    const int kx = bid & 7;

    // ---- Pm[0] = C2*C1, Pm[1] = C2, stage fc1 ----
    {
        const int o = tid >> 4, c = tid & 15;
        float s = 0.f;
        for (int k = 0; k < 16; ++k)
            s += conv_w[512 + o * 16 + k] * conv_w[256 + k * 16 + c];
        Pm[tid] = s;
    }
    Pm[256 + tid] = conv_w[512 + tid];
    #pragma unroll
    for (int k = 0; k < 4; ++k) fc1_s[tid + k * 256] = fc1_w[tid + k * 256];

    // ---- X2 = sum of 64 partials ----
    {
        const int q = tid & 15, c = tid >> 4;
        float acc = 0.f;
        #pragma unroll
        for (int m = 0; m < 4; ++m) {
            const int rg = c + 16 * m;
            acc += P[((size_t)((b * 64 + rg) * 8 + kx)) * 16 + q];
        }
        red2[c * 16 + q] = acc;
    }
    __syncthreads();
    if (tid < 16) {
        float s = 0.f;
        #pragma unroll
        for (int c = 0; c < 16; ++c) s += red2[c * 16 + tid];
        X2[tid] = s;
    }
    __syncthreads();

    // ---- recurrence: thread = (o,ky), tid < 128 ----
    const bool act = (tid < 128);
    const int o = tid >> 3, ky = tid & 7;
    if (act) {
        const float inv = 1.f / (512.f * 512.f);
        float xr0 = fc0_w[o] * X2[ky] * inv;
        float xi0 = fc0_w[o] * X2[8 + ky] * inv;
        if (kx == 0 && ky == 0) xr0 += fc0_b[o];
        Xr[o * 8 + ky] = xr0; Xi[o * 8 + ky] = xi0;
        Ar[o * 8 + ky] = 0.f; Ai[o * 8 + ky] = 0.f;
    }
    __syncthreads();

    for (int dd = 0; dd < 3; ++dd) {
        if (act) {
            float fr = 0.f, fi = 0.f;
            const float* wrp = spec_wr + (size_t)dd * SPEC_D + o * 64 + kx * 8 + ky;
            const float* wip = spec_wi + (size_t)dd * SPEC_D + o * 64 + kx * 8 + ky;
            #pragma unroll
            for (int i = 0; i < 16; ++i) {
                const float wre = wrp[i * 1024];
                const float wim = wip[i * 1024];
                const float xr0 = Xr[i * 8 + ky], xi0 = Xi[i * 8 + ky];
                fr += xr0 * wre - xi0 * wim;
                fi += xr0 * wim + xi0 * wre;
            }
            Fr[o * 8 + ky] = fr; Fi[o * 8 + ky] = fi;
        }
        __syncthreads();
        float xnr = 0.f, xni = 0.f;
        if (act) {
            float ar, ai;
            if (dd == 2) {
                ar = Fr[o * 8 + ky]; ai = Fi[o * 8 + ky];
            } else {
                ar = 0.f; ai = 0.f;
                #pragma unroll
                for (int c = 0; c < 16; ++c) {
                    const float pv = Pm[dd * 256 + o * 16 + c];
                    ar = fmaf(pv, Fr[c * 8 + ky], ar);
                    ai = fmaf(pv, Fi[c * 8 + ky], ai);
                }
            }
            Ar[o * 8 + ky] += ar; Ai[o * 8 + ky] += ai;
            if (dd < 2) {
                const float fr0 = Fr[o * 8 + ky], fi0 = Fi[o * 8 + ky];
                if (ky == 0) {
                    if (kx == 0) { xnr = fr0; xni = 0.f; }
                    else         { xnr = 0.5f * fr0; xni = 0.5f * fi0; }
                } else { xnr = fr0; xni = fi0; }
                #pragma unroll
                for (int c = 0; c < 16; ++c) {
                    const float cc = conv_w[dd * 256 + o * 16 + c];
                    xnr = fmaf(cc, Xr[c * 8 + ky], xnr);
                    xni = fmaf(cc, Xi[c * 8 + ky], xni);
                }
                if (kx == 0 && ky == 0) xnr += conv_b[dd * 16 + o];
            }
        }
        __syncthreads();
        if (act && dd < 2) { Xr[o * 8 + ky] = xnr; Xi[o * 8 + ky] = xni; }
        __syncthreads();
    }

    // ---- fold fc1 -> AH[b,hd,ky,kx] ----
    #pragma unroll
    for (int k2 = 0; k2 < 2; ++k2) {
        const int idx = tid + k2 * 256;      // hd*8 + ky2
        const int hd = idx >> 3, ky2 = idx & 7;
        float ar = 0.f, ai = 0.f;
        #pragma unroll
        for (int c = 0; c < 16; ++c) {
            const float f = fc1_s[c * 64 + hd];
            ar = fmaf(f, Ar[c * 8 + ky2], ar);
            ai = fmaf(f, Ai[c * 8 + ky2], ai);
        }
        const float ck = (ky2 == 0) ? 1.f : 2.f;    // Hermitian doubling
        const size_t off = ((((size_t)(b * 64 + hd)) * 8 + ky2) * 8 + kx) * 2;
        AH[off]     = ck * ar;
        AH[off + 1] = ck * ai;
    }

    // ---- kx==0: per-batch gvec/Kvec copies (weight-only math) ----
    if (kx == 0) {
        if (tid < 16) {
            float su = 0.f, sb = 0.f;
            for (int c = 0; c < 16; ++c) {
                su += conv_w[tid * 16 + c] * fc0_w[c];
                sb += conv_w[tid * 16 + c] * fc0_b[c];
            }
            ps[tid] = su; ps[16 + tid] = sb;
        }
        __syncthreads();
        if (tid < 16) {
            float dv = 0.f, ev = conv_b[32 + tid];
            for (int k = 0; k < 16; ++k) {
                dv += Pm[tid * 16 + k] * ps[k];
                ev += Pm[tid * 16 + k] * (ps[16 + k] + conv_b[k]);
                ev += conv_w[512 + tid * 16 + k] * conv_b[16 + k];
            }
            ps[32 + tid] = dv; ps[48 + tid] = ev;
        }
        __syncthreads();
        if (tid < 64) {
            float g = 0.f, K = fc1_b[tid];
            for (int c = 0; c < 16; ++c) {
                g = fmaf(fc1_w[c * 64 + tid], ps[32 + c], g);
                K = fmaf(fc1_w[c * 64 + tid], ps[48 + c], K);
            }
            gv[b * 64 + tid] = g;
            Kv[b * 64 + tid] = K;
        }
    }
}

// ---------------------------------------------------------------------------
// k_head (MFMA, fp16): 1024 blocks x 256 threads, wave = row.
// R11 configuration — the verified best (116.3 us total).  Dual px-tile
// iterations (8 independent MFMAs + two epilogues), 4-accumulator epilogue
// tree, next-iter b/x prefetch.  4 blocks/CU (32 KB LDS), VGPR 52, no spill
// — R13/R14/R15 proved any higher occupancy ask spills the ~100-unified-reg
// working set to scratch (FETCH 55-300 MB) and regresses 1.5-2x.
// ---------------------------------------------------------------------------
__global__ __launch_bounds__(256, 4) void k_head(
        const float* __restrict__ x, const float* __restrict__ AH,
        const float* __restrict__ gv, const float* __restrict__ Kv,
        const float* __restrict__ fc2_w, const float* __restrict__ fc2_b,
        float* __restrict__ out) {
    __shared__ __align__(16) _Float16 Ef[2][512][8];    // [cos/-sin][px][k] 16KB
    __shared__ __align__(16) _Float16 Apk[4][4][64][8]; // [row][kb][hd][j]  16KB

    const int tid  = threadIdx.x;
    const int lane = tid & 63;
    const int rl   = tid >> 6;           // wave = local row
    const int b    = blockIdx.x >> 7;
    const int rp   = blockIdx.x & 127;
    const int row  = rp * 4 + rl;

    // ---- E basis build (cooperative, 2 px per thread) ----
    #pragma unroll
    for (int pxi = 0; pxi < 2; ++pxi) {
        const int px = tid + pxi * 256;
        float c1, s1;
        __sincosf(ANG512 * (float)px, &s1, &c1);
        float ck = 1.f, sk = 0.f;        // k = 0
        #pragma unroll
        for (int k = 0; k < 8; ++k) {
            Ef[0][px][k] = (_Float16)ck;     // cos(k th px)
            Ef[1][px][k] = (_Float16)(-sk);  // -sin(k th px)
            const float cn = ck * c1 - sk * s1;
            const float sn = sk * c1 + ck * s1;
            ck = cn; sk = sn;
        }
    }

    // ---- gh / w2 per-lane preload (hd = t*16 + (lane>>4)*4 + v) ----
    float ghr[16], w2r[16];
    {
        const int lg = lane >> 4;
        #pragma unroll
        for (int t = 0; t < 4; ++t)
            #pragma unroll
            for (int v = 0; v < 4; ++v) {
                const int hd = t * 16 + lg * 4 + v;
                ghr[t * 4 + v] = gv[b * 64 + hd];
                w2r[t * 4 + v] = fc2_w[hd];
            }
    }

    // ---- WH build (fp32) -> fp16 hi/lo into Apk[rl] ----
    {
        float c1, s1;
        __sincosf(ANG512 * (float)row, &s1, &c1);
        float ctr[8], str[8];
        ctr[0] = 1.f; str[0] = 0.f; ctr[1] = c1; str[1] = s1;
        const float c2k = 2.f * c1;
        #pragma unroll
        for (int k = 2; k < 8; ++k) {
            ctr[k] = fmaf(c2k, ctr[k - 1], -ctr[k - 2]);
            str[k] = fmaf(c2k, str[k - 1], -str[k - 2]);
        }
        #pragma unroll
        for (int j = 0; j < 8; ++j) {
            const int idx = lane + j * 64;   // hd*8 + ky
            const int hd = idx >> 3, ky = idx & 7;
            const float4* ap = (const float4*)(AH + ((size_t)(b * 64 + hd) * 8 + ky) * 16);
            const float4 a0 = ap[0], a1 = ap[1], a2 = ap[2], a3 = ap[3];
            float wr = a0.x, wi = a0.y;      // kx=0
            wr = fmaf(a0.z, ctr[1], wr); wr = fmaf(-a0.w, str[1], wr);
            wi = fmaf(a0.z, str[1], wi); wi = fmaf(a0.w, ctr[1], wi);
            wr = fmaf(a1.x, ctr[2], wr); wr = fmaf(-a1.y, str[2], wr);
            wi = fmaf(a1.x, str[2], wi); wi = fmaf(a1.y, ctr[2], wi);
            wr = fmaf(a1.z, ctr[3], wr); wr = fmaf(-a1.w, str[3], wr);
            wi = fmaf(a1.z, str[3], wi); wi = fmaf(a1.w, ctr[3], wi);
            wr = fmaf(a2.x, ctr[4], wr); wr = fmaf(-a2.y, str[4], wr);
            wi = fmaf(a2.x, str[4], wi); wi = fmaf(a2.y, ctr[4], wi);
            wr = fmaf(a2.z, ctr[5], wr); wr = fmaf(-a2.w, str[5], wr);
            wi = fmaf(a2.z, str[5], wi); wi = fmaf(a2.w, ctr[5], wi);
            wr = fmaf(a3.x, ctr[6], wr); wr = fmaf(-a3.y, str[6], wr);
            wi = fmaf(a3.x, str[6], wi); wi = fmaf(a3.y, ctr[6], wi);
            wr = fmaf(a3.z, ctr[7], wr); wr = fmaf(-a3.w, str[7], wr);
            wi = fmaf(a3.w, ctr[7], wi); wi = fmaf(a3.z, str[7], wi);
            if (ky == 0) wr += Kv[b * 64 + hd];
            const _Float16 hr  = (_Float16)wr;
            const _Float16 hi_ = (_Float16)wi;
            Apk[rl][0][hd][ky] = hr;                          // WHr hi (K 0..7)
            Apk[rl][1][hd][ky] = hi_;                         // WHi hi (K 8..15)
            Apk[rl][2][hd][ky] = (_Float16)(wr - (float)hr);  // WHr lo (K 16..23)
            Apk[rl][3][hd][ky] = (_Float16)(wi - (float)hi_); // WHi lo (K 24..31)
        }
    }
    __syncthreads();

    // ---- A fragments (resident in VGPRs) ----
    f16x8 a1[4];
    {
        const int kb = lane >> 4, m = lane & 15;
        #pragma unroll
        for (int t = 0; t < 4; ++t)
            a1[t] = *(const f16x8*)&Apk[rl][kb][t * 16 + m][0];
    }

    // ---- dual-tile pipelined MFMA + epilogue: 16 iters x 2 px-tiles ----
    const int eb = (lane >> 4) & 1, n = lane & 15;
    const float fc2b = fc2_b[0];
    const float* xrow = x + ((size_t)(b * NH + row)) * NW;
    float* orow = out + ((size_t)(b * NH + row)) * NW;

    f16x8 bn0 = *(const f16x8*)&Ef[eb][n][0];
    f16x8 bn1 = *(const f16x8*)&Ef[eb][16 + n][0];
    float xn0 = xrow[n];
    float xn1 = xrow[16 + n];

    #pragma unroll 2
    for (int it = 0; it < 16; ++it) {
        const f16x8 b0 = bn0, b1 = bn1;
        const float x0 = xn0, x1 = xn1;
        if (it < 15) {                        // prefetch iter+1 (both tiles)
            const int pb = (it + 1) * 32 + n;
            bn0 = *(const f16x8*)&Ef[eb][pb][0];
            bn1 = *(const f16x8*)&Ef[eb][pb + 16][0];
            xn0 = xrow[pb];
            xn1 = xrow[pb + 16];
        }
        f32x4 c0[4], c1[4];
        #pragma unroll
        for (int t = 0; t < 4; ++t) {
            c0[t] = (f32x4){0.f, 0.f, 0.f, 0.f};
            c1[t] = (f32x4){0.f, 0.f, 0.f, 0.f};
            c0[t] = __builtin_amdgcn_mfma_f32_16x16x32_f16(a1[t], b0, c0[t], 0, 0, 0);
            c1[t] = __builtin_amdgcn_mfma_f32_16x16x32_f16(a1[t], b1, c1[t], 0, 0, 0);
        }
        // epilogue, 4 independent accumulator chains per tile
        float p0[4] = {0.f, 0.f, 0.f, 0.f};
        float p1[4] = {0.f, 0.f, 0.f, 0.f};
        #pragma unroll
        for (int t = 0; t < 4; ++t)
            #pragma unroll
            for (int v = 0; v < 4; ++v) {
                float s0 = fmaf(ghr[t * 4 + v], x0, c0[t][v]);
                float s1 = fmaf(ghr[t * 4 + v], x1, c1[t][v]);
                s0 = fmaxf(s0, 0.f);
                s1 = fmaxf(s1, 0.f);
                p0[v] = fmaf(s0, w2r[t * 4 + v], p0[v]);
                p1[v] = fmaf(s1, w2r[t * 4 + v], p1[v]);
            }
        float v0 = (p0[0] + p0[1]) + (p0[2] + p0[3]);
        float v1 = (p1[0] + p1[1]) + (p1[2] + p1[3]);
        v0 += __shfl_xor(v0, 16);
        v1 += __shfl_xor(v1, 16);
        v0 += __shfl_xor(v0, 32);
        v1 += __shfl_xor(v1, 32);
        if (lane < 16) {
            orow[it * 32 + lane]      = v0 + fc2b;
            orow[it * 32 + 16 + lane] = v1 + fc2b;
        }
    }
}

// ---------------------------------------------------------------------------
extern "C" void kernel_launch(void* const* d_in, const int* in_sizes, int n_in,
                              void* d_out, int out_size, void* d_ws, size_t ws_size,
                              hipStream_t stream) {
    const float* x       = (const float*)d_in[0];
    const float* fc0_w   = (const float*)d_in[1];
    const float* fc0_b   = (const float*)d_in[2];
    const float* spec_wr = (const float*)d_in[3];
    const float* spec_wi = (const float*)d_in[4];
    const float* conv_w  = (const float*)d_in[5];
    const float* conv_b  = (const float*)d_in[6];
    const float* fc1_w   = (const float*)d_in[7];
    const float* fc1_b   = (const float*)d_in[8];
    const float* fc2_w   = (const float*)d_in[9];
    const float* fc2_b   = (const float*)d_in[10];
    float* outp = (float*)d_out;

    char* ws = (char*)d_ws;
    float* P  = (float*)ws;                       // 8*64*8*16 floats = 256 KB
    float* AH = (float*)(ws + 262144);            // 8*64*64*2 floats = 256 KB
    float* gv = (float*)(ws + 524288);            // 8*64 floats = 2 KB
    float* Kv = (float*)(ws + 526336);            // 8*64 floats = 2 KB

    k_pre<<<512, 256, 0, stream>>>(x, P);
    k_modes<<<64, 256, 0, stream>>>(P, spec_wr, spec_wi, conv_w, conv_b,
                                    fc0_w, fc0_b, fc1_w, fc1_b, AH, gv, Kv);
    k_head<<<1024, 256, 0, stream>>>(x, AH, gv, Kv, fc2_w, fc2_b, outp);
}